// Round 5
// baseline (350.541 us; speedup 1.0000x reference)
//
#include <hip/hip_runtime.h>

// LSTM B=4096, T=2048, H=4 + linear head. Round-4 transposed 16-lane layout
// (lane r: gate g0=r&3 of column jc=r>>2; all DPP, no LDS), now with TWO
// sequences per 16-lane row (A=2q, B=2q+1), HAND-INTERLEAVED statement by
// statement. Rationale (r1-r4 post-mortem): wall/step = in-order issue +
// ~150cyc uncovered chain stall (4 serial transcendentals ~20cyc each +
// 2 DPP stages + FMA stages). Two independent chains with every A-op
// adjacent to its B-twin let each chain's issue hide inside the other's
// stalls (round-2's failure was the compiler emitting the chains as
// sequential blocks; adjacency prevents that). 512 waves as 512x64 blocks
// -> 2 waves/CU on separate SIMDs.
// Activation scales (log2 e) pre-folded into weights; cell state pre-scaled
// by 2*log2e so tanh(c) needs no multiply on the chain; b_lin/4 folded into
// the per-quad y FMA.

#define L2E 1.44269504088896340736f

constexpr int TLEN = 2048;

template <int CTRL>
__device__ __forceinline__ float dpp(float v) {
    return __int_as_float(
        __builtin_amdgcn_mov_dpp(__float_as_int(v), CTRL, 0xF, 0xF, true));
}
__device__ __forceinline__ float fexp2(float x) { return __builtin_amdgcn_exp2f(x); }
__device__ __forceinline__ float frcp(float x)  { return __builtin_amdgcn_rcpf(x); }

__global__ __launch_bounds__(64) void lstm16x2_kernel(
    const float* __restrict__ x,      // [B, T]
    const float* __restrict__ W_ih,   // [16]
    const float* __restrict__ W_hh,   // [16, 4]
    const float* __restrict__ b_ih,   // [16]
    const float* __restrict__ b_hh,   // [16]
    const float* __restrict__ W_lin,  // [4]
    const float* __restrict__ b_lin,  // [1]
    float* __restrict__ out)          // [B, T]
{
    const int tid = blockIdx.x * 64 + threadIdx.x;
    const int row = tid >> 4;         // 16-lane row; handles seqs 2row, 2row+1
    const int r   = tid & 15;
    const int g0  = r & 3;            // gate owned: 0=i 1=f 2=g 3=o
    const int jc  = r >> 2;           // hidden column owned by this quad
    const int wrow = g0 * 4 + jc;     // row in the [16,*] weight blocks

    // sigmoid(z) = 1/(1+exp2(-z*L2E))   -> scale i,f,o rows by -L2E
    // tanh(z)    = 1-2/(1+exp2(2z*L2E)) -> scale g row by +2*L2E
    const float s = (g0 == 2) ? (2.0f * L2E) : (-L2E);

    const float wih  = W_ih[wrow] * s;
    const float bias = (b_ih[wrow] + b_hh[wrow]) * s;
    const float wh_0 = W_hh[wrow * 4 + jc]       * s;
    const float wh_1 = W_hh[wrow * 4 + (jc ^ 1)] * s;
    const float wh_2 = W_hh[wrow * 4 + (jc ^ 2)] * s;
    const float wh_3 = W_hh[wrow * 4 + (jc ^ 3)] * s;
    // v = Aact * rcp(1+exp2(z)) + Bact: i/f/o -> sigmoid; g -> 2*L2E*tanh.
    const float Aact = (g0 == 2) ? (-4.0f * L2E) : 1.0f;
    const float Bact = (g0 == 2) ? ( 2.0f * L2E) : 0.0f;

    const float wlin  = W_lin[jc];
    const float blinq = b_lin[0] * 0.25f;   // summed over 4 quads -> b_lin

    const float* xpA = x + (size_t)(2 * row) * TLEN;
    const float* xpB = xpA + TLEN;
    float*       opA = out + (size_t)(2 * row) * TLEN;
    float*       opB = opA + TLEN;

    float hA = 0.0f, CA = 0.0f;   // quad-uniform h and 2L2E-scaled cell
    float hB = 0.0f, CB = 0.0f;

    // x stream: 8 steps (2x float4) per chain per group, prefetched one
    // group ahead.
    float4 xaA = *(const float4*)(xpA);
    float4 xbA = *(const float4*)(xpA + 4);
    float4 xaB = *(const float4*)(xpB);
    float4 xbB = *(const float4*)(xpB + 4);

    for (int t = 0; t < TLEN; t += 8) {
        int tn = t + 8;
        if (tn > TLEN - 8) tn = 0;  // safe dummy address for last group
        const float4 xaA_n = *(const float4*)(xpA + tn);
        const float4 xbA_n = *(const float4*)(xpA + tn + 4);
        const float4 xaB_n = *(const float4*)(xpB + tn);
        const float4 xbB_n = *(const float4*)(xpB + tn + 4);

        const float xsA[8] = {xaA.x, xaA.y, xaA.z, xaA.w, xbA.x, xbA.y, xbA.z, xbA.w};
        const float xsB[8] = {xaB.x, xaB.y, xaB.z, xaB.w, xbB.x, xbB.y, xbB.z, xbB.w};
        float z0A[8], z0B[8], yA[8], yB[8];
#pragma unroll
        for (int u = 0; u < 8; ++u) {
            z0A[u] = fmaf(xsA[u], wih, bias);
            z0B[u] = fmaf(xsB[u], wih, bias);
        }

#pragma unroll
        for (int u = 0; u < 8; ++u) {
            // Cross-quad h gather (direction-free DPP; h quad-uniform).
            const float h1A = dpp<0x141>(hA);  // row_half_mirror -> jc^1
            const float h1B = dpp<0x141>(hB);
            const float h2A = dpp<0x128>(hA);  // row_ror:8       -> jc^2
            const float h2B = dpp<0x128>(hB);
            const float h3A = dpp<0x140>(hA);  // row_mirror      -> jc^3
            const float h3B = dpp<0x140>(hB);

            float zA = fmaf(wh_0, hA, z0A[u]);
            float zB = fmaf(wh_0, hB, z0B[u]);
            zA = fmaf(wh_1, h1A, zA);
            zB = fmaf(wh_1, h1B, zB);
            zA = fmaf(wh_2, h2A, zA);
            zB = fmaf(wh_2, h2B, zB);
            zA = fmaf(wh_3, h3A, zA);
            zB = fmaf(wh_3, h3B, zB);

            const float eA = fexp2(zA);
            const float eB = fexp2(zB);
            const float dA = 1.0f + eA;
            const float dB = 1.0f + eB;
            const float rA = frcp(dA);
            const float rB = frcp(dB);
            const float vA = fmaf(Aact, rA, Bact);
            const float vB = fmaf(Aact, rB, Bact);

            // All four gates of the column live in this quad: broadcast.
            const float ivA = dpp<0x00>(vA);
            const float ivB = dpp<0x00>(vB);
            const float fvA = dpp<0x55>(vA);
            const float fvB = dpp<0x55>(vB);
            const float gvA = dpp<0xAA>(vA);
            const float gvB = dpp<0xAA>(vB);
            const float ovA = dpp<0xFF>(vA);
            const float ovB = dpp<0xFF>(vB);

            const float mA = ivA * gvA;
            const float mB = ivB * gvB;
            CA = fmaf(fvA, CA, mA);            // scaled cell update
            CB = fmaf(fvB, CB, mB);

            const float e2A = fexp2(CA);
            const float e2B = fexp2(CB);
            const float d2A = 1.0f + e2A;
            const float d2B = 1.0f + e2B;
            const float r2A = frcp(d2A);
            const float r2B = frcp(d2B);
            const float tcA = fmaf(-2.0f, r2A, 1.0f);
            const float tcB = fmaf(-2.0f, r2B, 1.0f);

            hA = ovA * tcA;                    // quad-uniform again
            hB = ovB * tcB;

            // y = sum_jc wlin_jc h_jc + blin (blin/4 folded per quad).
            float pA = fmaf(wlin, hA, blinq);
            float pB = fmaf(wlin, hB, blinq);
            pA += dpp<0x128>(pA);
            pB += dpp<0x128>(pB);
            pA += dpp<0x141>(pA);
            pB += dpp<0x141>(pB);
            yA[u] = pA;
            yB[u] = pB;
        }

        if (r == 0) {
            *(float4*)(opA + t)     = make_float4(yA[0], yA[1], yA[2], yA[3]);
            *(float4*)(opA + t + 4) = make_float4(yA[4], yA[5], yA[6], yA[7]);
            *(float4*)(opB + t)     = make_float4(yB[0], yB[1], yB[2], yB[3]);
            *(float4*)(opB + t + 4) = make_float4(yB[4], yB[5], yB[6], yB[7]);
        }

        xaA = xaA_n; xbA = xbA_n;
        xaB = xaB_n; xbB = xbB_n;
    }
}

extern "C" void kernel_launch(void* const* d_in, const int* in_sizes, int n_in,
                              void* d_out, int out_size, void* d_ws, size_t ws_size,
                              hipStream_t stream) {
    const float* x     = (const float*)d_in[0];
    const float* W_ih  = (const float*)d_in[1];
    const float* W_hh  = (const float*)d_in[2];
    const float* b_ih  = (const float*)d_in[3];
    const float* b_hh  = (const float*)d_in[4];
    const float* W_lin = (const float*)d_in[5];
    const float* b_lin = (const float*)d_in[6];
    float* out = (float*)d_out;

    const int B = in_sizes[0] / TLEN;          // 4096
    const int threads = (B / 2) * 16;          // 16 lanes per sequence PAIR
    const int block = 64;                      // 1 wave/block
    const int grid = threads / block;          // 512 blocks -> 2 waves/CU

    lstm16x2_kernel<<<grid, block, 0, stream>>>(x, W_ih, W_hh, b_ih, b_hh,
                                                W_lin, b_lin, out);
}